// Round 1
// baseline (152.689 us; speedup 1.0000x reference)
//
#include <hip/hip_runtime.h>
#include <hip/hip_bf16.h>

// LSTM cell fused: C = [x|h] @ [Wx|Wh]^T (gate-interleaved N), epilogue fused.
// B=4096, IN=1024, H=1024  ->  GEMM M=4096, N=4096 (j*4+g), K=2048.

constexpr int Mdim = 4096;
constexpr int Ndim = 4096;
constexpr int Kdim = 2048;
constexpr int Hdim = 1024;
constexpr int BM = 128;
constexpr int BN = 128;
constexpr int BK = 64;

using short8 = __attribute__((ext_vector_type(8))) short;
using f32x4  = __attribute__((ext_vector_type(4))) float;

__device__ __forceinline__ float sigmoid_(float x) {
    return 1.f / (1.f + __expf(-x));
}
__device__ __forceinline__ float tanh_(float x) {
    // bounded inputs here (|x| < ~8), exp form is safe
    float e = __expf(2.f * x);
    return (e - 1.f) / (e + 1.f);
}

// ---- build A = [x | h] as bf16 [4096][2048] ----
__global__ void build_A(const float* __restrict__ x, const float* __restrict__ h,
                        __hip_bfloat16* __restrict__ A) {
    int idx = blockIdx.x * 256 + threadIdx.x;   // 1,048,576 threads, 8 elems each
    int row = idx >> 8;                          // 256 chunks of 8 per row
    int c8  = (idx & 255) * 8;
    const float* src = (c8 < 1024) ? (x + (size_t)row * 1024 + c8)
                                   : (h + (size_t)row * 1024 + (c8 - 1024));
    float4 f0 = ((const float4*)src)[0];
    float4 f1 = ((const float4*)src)[1];
    union { short8 v; __hip_bfloat16 e[8]; } u;
    u.e[0] = __float2bfloat16(f0.x); u.e[1] = __float2bfloat16(f0.y);
    u.e[2] = __float2bfloat16(f0.z); u.e[3] = __float2bfloat16(f0.w);
    u.e[4] = __float2bfloat16(f1.x); u.e[5] = __float2bfloat16(f1.y);
    u.e[6] = __float2bfloat16(f1.z); u.e[7] = __float2bfloat16(f1.w);
    *(short8*)(A + (size_t)row * Kdim + c8) = u.v;
}

// ---- build B: row n = j*4+g ; cols = [Wx_g[j,:] | Wh_g[j,:]] as bf16 ----
__global__ void build_B(const float* __restrict__ Wxi, const float* __restrict__ Whi,
                        const float* __restrict__ Wxf, const float* __restrict__ Whf,
                        const float* __restrict__ Wxg, const float* __restrict__ Whg,
                        const float* __restrict__ Wxo, const float* __restrict__ Who,
                        __hip_bfloat16* __restrict__ B) {
    int idx = blockIdx.x * 256 + threadIdx.x;
    int n  = idx >> 8;
    int c8 = (idx & 255) * 8;
    int j = n >> 2, g = n & 3;
    const float* Wx = (g == 0) ? Wxi : (g == 1) ? Wxf : (g == 2) ? Wxg : Wxo;
    const float* Wh = (g == 0) ? Whi : (g == 1) ? Whf : (g == 2) ? Whg : Who;
    const float* src = (c8 < 1024) ? (Wx + (size_t)j * 1024 + c8)
                                   : (Wh + (size_t)j * 1024 + (c8 - 1024));
    float4 f0 = ((const float4*)src)[0];
    float4 f1 = ((const float4*)src)[1];
    union { short8 v; __hip_bfloat16 e[8]; } u;
    u.e[0] = __float2bfloat16(f0.x); u.e[1] = __float2bfloat16(f0.y);
    u.e[2] = __float2bfloat16(f0.z); u.e[3] = __float2bfloat16(f0.w);
    u.e[4] = __float2bfloat16(f1.x); u.e[5] = __float2bfloat16(f1.y);
    u.e[6] = __float2bfloat16(f1.z); u.e[7] = __float2bfloat16(f1.w);
    *(short8*)(B + (size_t)n * Kdim + c8) = u.v;
}

// ---- fused GEMM + LSTM epilogue ----
__launch_bounds__(256, 2)
__global__ void lstm_gemm(const __hip_bfloat16* __restrict__ A,
                          const __hip_bfloat16* __restrict__ B,
                          const float* __restrict__ c_prev,
                          const float* __restrict__ b_i, const float* __restrict__ b_f,
                          const float* __restrict__ b_g, const float* __restrict__ b_o,
                          float* __restrict__ out_h, float* __restrict__ out_c) {
    __shared__ __hip_bfloat16 As[BM * BK];
    __shared__ __hip_bfloat16 Bs[BN * BK];

    const int tid  = threadIdx.x;
    const int lane = tid & 63;
    const int w    = tid >> 6;
    const int wr   = w >> 1, wc = w & 1;
    const int l15  = lane & 15, lhi = lane >> 4;

    // XCD-aware swizzle (nwg = 1024, divisible by 8)
    int bid = blockIdx.x;
    int swz = (bid & 7) * (1024 / 8) + (bid >> 3);
    const int bm = (swz >> 5) * BM;
    const int bn = (swz & 31) * BN;

    f32x4 acc[4][4];
#pragma unroll
    for (int a = 0; a < 4; ++a)
#pragma unroll
        for (int b = 0; b < 4; ++b)
            acc[a][b] = (f32x4){0.f, 0.f, 0.f, 0.f};

    for (int kt = 0; kt < Kdim; kt += BK) {
        __syncthreads();   // previous reads done before overwrite
#pragma unroll
        for (int it = 0; it < 4; ++it) {
            int off = it * 4096 + tid * 16;    // byte offset within 16KB tile
            int row = off >> 7;                // /128 B per row
            int col = (off & 127) >> 1;        // bf16 col within row
            __builtin_amdgcn_global_load_lds(
                (const __attribute__((address_space(1))) unsigned*)(A + (size_t)(bm + row) * Kdim + kt + col),
                (__attribute__((address_space(3))) unsigned*)((char*)As + off), 16, 0, 0);
            __builtin_amdgcn_global_load_lds(
                (const __attribute__((address_space(1))) unsigned*)(B + (size_t)(bn + row) * Kdim + kt + col),
                (__attribute__((address_space(3))) unsigned*)((char*)Bs + off), 16, 0, 0);
        }
        __syncthreads();   // loads complete (compiler drains vmcnt before barrier)

#pragma unroll
        for (int kk = 0; kk < 2; ++kk) {
            short8 af[4], bfr[4];
#pragma unroll
            for (int a = 0; a < 4; ++a)
                af[a] = *(const short8*)&As[(wr * 64 + a * 16 + l15) * BK + kk * 32 + lhi * 8];
#pragma unroll
            for (int b = 0; b < 4; ++b)
                bfr[b] = *(const short8*)&Bs[(wc * 64 + b * 16 + l15) * BK + kk * 32 + lhi * 8];
#pragma unroll
            for (int a = 0; a < 4; ++a)
#pragma unroll
                for (int b = 0; b < 4; ++b)
                    acc[a][b] = __builtin_amdgcn_mfma_f32_16x16x32_bf16(af[a], bfr[b], acc[a][b], 0, 0, 0);
        }
    }

    // ---- fused LSTM epilogue ----
    // column n = bn + wc*64 + b*16 + l15 ; j = n>>2 ; gate = n&3
    const int g = lane & 3;
    const float* myb = (g == 0) ? b_i : (g == 1) ? b_f : (g == 2) ? b_g : b_o;
    float bias[4];
    int   jcol[4];
#pragma unroll
    for (int b = 0; b < 4; ++b) {
        int n = bn + wc * 64 + b * 16 + l15;
        jcol[b] = n >> 2;
        bias[b] = myb[jcol[b]];
    }
    const int base = lane & ~3;
#pragma unroll
    for (int a = 0; a < 4; ++a) {
        int mbase = bm + wr * 64 + a * 16 + lhi * 4;
#pragma unroll
        for (int b = 0; b < 4; ++b) {
            int j = jcol[b];
#pragma unroll
            for (int r = 0; r < 4; ++r) {
                float v = acc[a][b][r] + bias[b];
                float vi = __shfl(v, base + 0, 64);
                float vf = __shfl(v, base + 1, 64);
                float vg = __shfl(v, base + 2, 64);
                float vo = __shfl(v, base + 3, 64);
                int m = mbase + r;
                float it = sigmoid_(vi);
                float ft = sigmoid_(vf);
                float gt = tanh_(vg);
                float ot = sigmoid_(vo);
                float cp = c_prev[(size_t)m * Hdim + j];
                float ct = ft * cp + it * gt;
                float ht = ot * tanh_(ct);
                if (g == 0)      out_h[(size_t)m * Hdim + j] = ht;
                else if (g == 1) out_c[(size_t)m * Hdim + j] = ct;
            }
        }
    }
}

extern "C" void kernel_launch(void* const* d_in, const int* in_sizes, int n_in,
                              void* d_out, int out_size, void* d_ws, size_t ws_size,
                              hipStream_t stream) {
    const float* x_t    = (const float*)d_in[0];
    const float* h_prev = (const float*)d_in[1];
    const float* c_prev = (const float*)d_in[2];
    const float* W_xi   = (const float*)d_in[3];
    const float* W_hi   = (const float*)d_in[4];
    const float* b_i    = (const float*)d_in[5];
    const float* W_xf   = (const float*)d_in[6];
    const float* W_hf   = (const float*)d_in[7];
    const float* b_f    = (const float*)d_in[8];
    const float* W_xg   = (const float*)d_in[9];
    const float* W_hg   = (const float*)d_in[10];
    const float* b_g    = (const float*)d_in[11];
    const float* W_xo   = (const float*)d_in[12];
    const float* W_ho   = (const float*)d_in[13];
    const float* b_o    = (const float*)d_in[14];

    float* out_h = (float*)d_out;
    float* out_c = out_h + (size_t)Mdim * Hdim;

    __hip_bfloat16* Abf = (__hip_bfloat16*)d_ws;
    __hip_bfloat16* Bbf = Abf + (size_t)Mdim * Kdim;

    build_A<<<4096, 256, 0, stream>>>(x_t, h_prev, Abf);
    build_B<<<4096, 256, 0, stream>>>(W_xi, W_hi, W_xf, W_hf, W_xg, W_hg, W_xo, W_ho, Bbf);

    lstm_gemm<<<dim3((Mdim / BM) * (Ndim / BN)), 256, 0, stream>>>(
        Abf, Bbf, c_prev, b_i, b_f, b_g, b_o, out_h, out_c);
}

// Round 2
// 104.380 us; speedup vs baseline: 1.4628x; 1.4628x over previous
//
#include <hip/hip_runtime.h>
#include <hip/hip_bf16.h>

// LSTM cell fused: C = [x|h] @ [Wx|Wh]^T (gate-per-16col-fragment N layout),
// epilogue fused, shuffle-free.
// B=4096, IN=1024, H=1024  ->  GEMM M=4096, N=4096, K=2048.
// N mapping: n = ((j>>4)<<6) | (g<<4) | (j&15)  -> fragment index b == gate.

constexpr int Mdim = 4096;
constexpr int Ndim = 4096;
constexpr int Kdim = 2048;
constexpr int Hdim = 1024;
constexpr int BM = 128;
constexpr int BN = 128;
constexpr int BK = 64;

using short8 = __attribute__((ext_vector_type(8))) short;
using f32x4  = __attribute__((ext_vector_type(4))) float;

__device__ __forceinline__ float sigmoid_(float x) {
    return 1.f / (1.f + __expf(-x));
}
__device__ __forceinline__ float tanh_(float x) {
    float e = __expf(2.f * x);
    return (e - 1.f) / (e + 1.f);
}

// ---- build A = [x | h] as bf16 [4096][2048] ----
__global__ void build_A(const float* __restrict__ x, const float* __restrict__ h,
                        __hip_bfloat16* __restrict__ A) {
    int idx = blockIdx.x * 256 + threadIdx.x;   // 1,048,576 threads, 8 elems each
    int row = idx >> 8;
    int c8  = (idx & 255) * 8;
    const float* src = (c8 < 1024) ? (x + (size_t)row * 1024 + c8)
                                   : (h + (size_t)row * 1024 + (c8 - 1024));
    float4 f0 = ((const float4*)src)[0];
    float4 f1 = ((const float4*)src)[1];
    union { short8 v; __hip_bfloat16 e[8]; } u;
    u.e[0] = __float2bfloat16(f0.x); u.e[1] = __float2bfloat16(f0.y);
    u.e[2] = __float2bfloat16(f0.z); u.e[3] = __float2bfloat16(f0.w);
    u.e[4] = __float2bfloat16(f1.x); u.e[5] = __float2bfloat16(f1.y);
    u.e[6] = __float2bfloat16(f1.z); u.e[7] = __float2bfloat16(f1.w);
    *(short8*)(A + (size_t)row * Kdim + c8) = u.v;
}

// ---- build B: row n -> gate g=(n>>4)&3, unit j=((n>>6)<<4)|(n&15) ----
__global__ void build_B(const float* __restrict__ Wxi, const float* __restrict__ Whi,
                        const float* __restrict__ Wxf, const float* __restrict__ Whf,
                        const float* __restrict__ Wxg, const float* __restrict__ Whg,
                        const float* __restrict__ Wxo, const float* __restrict__ Who,
                        __hip_bfloat16* __restrict__ B) {
    int idx = blockIdx.x * 256 + threadIdx.x;
    int n  = idx >> 8;
    int c8 = (idx & 255) * 8;
    int g = (n >> 4) & 3;
    int j = ((n >> 6) << 4) | (n & 15);
    const float* Wx = (g == 0) ? Wxi : (g == 1) ? Wxf : (g == 2) ? Wxg : Wxo;
    const float* Wh = (g == 0) ? Whi : (g == 1) ? Whf : (g == 2) ? Whg : Who;
    const float* src = (c8 < 1024) ? (Wx + (size_t)j * 1024 + c8)
                                   : (Wh + (size_t)j * 1024 + (c8 - 1024));
    float4 f0 = ((const float4*)src)[0];
    float4 f1 = ((const float4*)src)[1];
    union { short8 v; __hip_bfloat16 e[8]; } u;
    u.e[0] = __float2bfloat16(f0.x); u.e[1] = __float2bfloat16(f0.y);
    u.e[2] = __float2bfloat16(f0.z); u.e[3] = __float2bfloat16(f0.w);
    u.e[4] = __float2bfloat16(f1.x); u.e[5] = __float2bfloat16(f1.y);
    u.e[6] = __float2bfloat16(f1.z); u.e[7] = __float2bfloat16(f1.w);
    *(short8*)(B + (size_t)n * Kdim + c8) = u.v;
}

// ---- fused GEMM + LSTM epilogue ----
__launch_bounds__(256, 4)
__global__ void lstm_gemm(const __hip_bfloat16* __restrict__ A,
                          const __hip_bfloat16* __restrict__ B,
                          const float* __restrict__ c_prev,
                          const float* __restrict__ b_i, const float* __restrict__ b_f,
                          const float* __restrict__ b_g, const float* __restrict__ b_o,
                          float* __restrict__ out_h, float* __restrict__ out_c) {
    __shared__ __hip_bfloat16 As[BM * BK];
    __shared__ __hip_bfloat16 Bs[BN * BK];

    const int tid  = threadIdx.x;
    const int lane = tid & 63;
    const int w    = tid >> 6;
    const int wr   = w >> 1, wc = w & 1;
    const int l15  = lane & 15, lhi = lane >> 4;

    // XCD-aware swizzle (nwg = 1024, divisible by 8)
    int bid = blockIdx.x;
    int swz = (bid & 7) * (1024 / 8) + (bid >> 3);
    const int bm = (swz >> 5) * BM;
    const int bn = (swz & 31) * BN;

    f32x4 acc[4][4];
#pragma unroll
    for (int a = 0; a < 4; ++a)
#pragma unroll
        for (int b = 0; b < 4; ++b)
            acc[a][b] = (f32x4){0.f, 0.f, 0.f, 0.f};

    for (int kt = 0; kt < Kdim; kt += BK) {
        __syncthreads();   // previous reads done before overwrite
#pragma unroll
        for (int it = 0; it < 4; ++it) {
            int off = it * 4096 + tid * 16;    // byte offset within 16KB tile
            int row = off >> 7;                // /128 B per row
            int col = (off & 127) >> 1;        // bf16 col within row
            __builtin_amdgcn_global_load_lds(
                (const __attribute__((address_space(1))) unsigned*)(A + (size_t)(bm + row) * Kdim + kt + col),
                (__attribute__((address_space(3))) unsigned*)((char*)As + off), 16, 0, 0);
            __builtin_amdgcn_global_load_lds(
                (const __attribute__((address_space(1))) unsigned*)(B + (size_t)(bn + row) * Kdim + kt + col),
                (__attribute__((address_space(3))) unsigned*)((char*)Bs + off), 16, 0, 0);
        }
        __syncthreads();   // loads complete (compiler drains vmcnt before barrier)

#pragma unroll
        for (int kk = 0; kk < 2; ++kk) {
            short8 af[4], bfr[4];
#pragma unroll
            for (int a = 0; a < 4; ++a)
                af[a] = *(const short8*)&As[(wr * 64 + a * 16 + l15) * BK + kk * 32 + lhi * 8];
#pragma unroll
            for (int b = 0; b < 4; ++b)
                bfr[b] = *(const short8*)&Bs[(wc * 64 + b * 16 + l15) * BK + kk * 32 + lhi * 8];
#pragma unroll
            for (int a = 0; a < 4; ++a)
#pragma unroll
                for (int b = 0; b < 4; ++b)
                    acc[a][b] = __builtin_amdgcn_mfma_f32_16x16x32_bf16(af[a], bfr[b], acc[a][b], 0, 0, 0);
        }
    }

    // ---- fused LSTM epilogue (shuffle-free) ----
    // column n = bn + wc*64 + b*16 + l15 ; gate = b ; j = ((bn+wc*64)>>6)*16 + l15
    const int j0 = ((bn + wc * 64) >> 6) * 16 + l15;
    const float bi = b_i[j0];
    const float bf_ = b_f[j0];
    const float bg = b_g[j0];
    const float bo = b_o[j0];

#pragma unroll
    for (int a = 0; a < 4; ++a) {
        int mbase = bm + wr * 64 + a * 16 + lhi * 4;
#pragma unroll
        for (int r = 0; r < 4; ++r) {
            int m = mbase + r;
            float vi = acc[a][0][r] + bi;
            float vf = acc[a][1][r] + bf_;
            float vg = acc[a][2][r] + bg;
            float vo = acc[a][3][r] + bo;
            float it = sigmoid_(vi);
            float ft = sigmoid_(vf);
            float gt = tanh_(vg);
            float ot = sigmoid_(vo);
            float cp = c_prev[(size_t)m * Hdim + j0];
            float ct = ft * cp + it * gt;
            float ht = ot * tanh_(ct);
            out_h[(size_t)m * Hdim + j0] = ht;
            out_c[(size_t)m * Hdim + j0] = ct;
        }
    }
}

extern "C" void kernel_launch(void* const* d_in, const int* in_sizes, int n_in,
                              void* d_out, int out_size, void* d_ws, size_t ws_size,
                              hipStream_t stream) {
    const float* x_t    = (const float*)d_in[0];
    const float* h_prev = (const float*)d_in[1];
    const float* c_prev = (const float*)d_in[2];
    const float* W_xi   = (const float*)d_in[3];
    const float* W_hi   = (const float*)d_in[4];
    const float* b_i    = (const float*)d_in[5];
    const float* W_xf   = (const float*)d_in[6];
    const float* W_hf   = (const float*)d_in[7];
    const float* b_f    = (const float*)d_in[8];
    const float* W_xg   = (const float*)d_in[9];
    const float* W_hg   = (const float*)d_in[10];
    const float* b_g    = (const float*)d_in[11];
    const float* W_xo   = (const float*)d_in[12];
    const float* W_ho   = (const float*)d_in[13];
    const float* b_o    = (const float*)d_in[14];

    float* out_h = (float*)d_out;
    float* out_c = out_h + (size_t)Mdim * Hdim;

    __hip_bfloat16* Abf = (__hip_bfloat16*)d_ws;
    __hip_bfloat16* Bbf = Abf + (size_t)Mdim * Kdim;

    build_A<<<4096, 256, 0, stream>>>(x_t, h_prev, Abf);
    build_B<<<4096, 256, 0, stream>>>(W_xi, W_hi, W_xf, W_hf, W_xg, W_hg, W_xo, W_ho, Bbf);

    lstm_gemm<<<dim3((Mdim / BM) * (Ndim / BN)), 256, 0, stream>>>(
        Abf, Bbf, c_prev, b_i, b_f, b_g, b_o, out_h, out_c);
}

// Round 3
// 91.315 us; speedup vs baseline: 1.6721x; 1.1431x over previous
//
#include <hip/hip_runtime.h>
#include <hip/hip_bf16.h>

// LSTM cell fused: C = [x|h] @ [Wx|Wh]^T (gate-per-16col-fragment N layout).
// GEMM M=4096, N=4096, K=2048, 256x256 tile, BK=32, 8 waves,
// 4-slot LDS ring with counted vmcnt (never drains in steady state),
// XOR-swizzled LDS (inverse-swizzled global source + swizzled ds_read).

constexpr int Mdim = 4096;
constexpr int Ndim = 4096;
constexpr int Kdim = 2048;
constexpr int Hdim = 1024;
constexpr int BM = 256;
constexpr int BN = 256;
constexpr int BK = 32;
constexpr int NT = Kdim / BK;   // 64 K-tiles

using short8 = __attribute__((ext_vector_type(8))) short;
using f32x4  = __attribute__((ext_vector_type(4))) float;

__device__ __forceinline__ float sigmoid_(float x) {
    return 1.f / (1.f + __expf(-x));
}
__device__ __forceinline__ float tanh_(float x) {
    float e = __expf(2.f * x);
    return (e - 1.f) / (e + 1.f);
}

// ---- build A = [x | h] as bf16 [4096][2048] ----
__global__ void build_A(const float* __restrict__ x, const float* __restrict__ h,
                        __hip_bfloat16* __restrict__ A) {
    int idx = blockIdx.x * 256 + threadIdx.x;
    int row = idx >> 8;
    int c8  = (idx & 255) * 8;
    const float* src = (c8 < 1024) ? (x + (size_t)row * 1024 + c8)
                                   : (h + (size_t)row * 1024 + (c8 - 1024));
    float4 f0 = ((const float4*)src)[0];
    float4 f1 = ((const float4*)src)[1];
    union { short8 v; __hip_bfloat16 e[8]; } u;
    u.e[0] = __float2bfloat16(f0.x); u.e[1] = __float2bfloat16(f0.y);
    u.e[2] = __float2bfloat16(f0.z); u.e[3] = __float2bfloat16(f0.w);
    u.e[4] = __float2bfloat16(f1.x); u.e[5] = __float2bfloat16(f1.y);
    u.e[6] = __float2bfloat16(f1.z); u.e[7] = __float2bfloat16(f1.w);
    *(short8*)(A + (size_t)row * Kdim + c8) = u.v;
}

// ---- build B: row n -> gate g=(n>>4)&3, unit j=((n>>6)<<4)|(n&15) ----
__global__ void build_B(const float* __restrict__ Wxi, const float* __restrict__ Whi,
                        const float* __restrict__ Wxf, const float* __restrict__ Whf,
                        const float* __restrict__ Wxg, const float* __restrict__ Whg,
                        const float* __restrict__ Wxo, const float* __restrict__ Who,
                        __hip_bfloat16* __restrict__ B) {
    int idx = blockIdx.x * 256 + threadIdx.x;
    int n  = idx >> 8;
    int c8 = (idx & 255) * 8;
    int g = (n >> 4) & 3;
    int j = ((n >> 6) << 4) | (n & 15);
    const float* Wx = (g == 0) ? Wxi : (g == 1) ? Wxf : (g == 2) ? Wxg : Wxo;
    const float* Wh = (g == 0) ? Whi : (g == 1) ? Whf : (g == 2) ? Whg : Who;
    const float* src = (c8 < 1024) ? (Wx + (size_t)j * 1024 + c8)
                                   : (Wh + (size_t)j * 1024 + (c8 - 1024));
    float4 f0 = ((const float4*)src)[0];
    float4 f1 = ((const float4*)src)[1];
    union { short8 v; __hip_bfloat16 e[8]; } u;
    u.e[0] = __float2bfloat16(f0.x); u.e[1] = __float2bfloat16(f0.y);
    u.e[2] = __float2bfloat16(f0.z); u.e[3] = __float2bfloat16(f0.w);
    u.e[4] = __float2bfloat16(f1.x); u.e[5] = __float2bfloat16(f1.y);
    u.e[6] = __float2bfloat16(f1.z); u.e[7] = __float2bfloat16(f1.w);
    *(short8*)(B + (size_t)n * Kdim + c8) = u.v;
}

// ---- fused GEMM + LSTM epilogue, 4-slot ring pipeline ----
__launch_bounds__(512, 1)
__global__ void lstm_gemm(const __hip_bfloat16* __restrict__ A,
                          const __hip_bfloat16* __restrict__ B,
                          const float* __restrict__ c_prev,
                          const float* __restrict__ b_i, const float* __restrict__ b_f,
                          const float* __restrict__ b_g, const float* __restrict__ b_o,
                          float* __restrict__ out_h, float* __restrict__ out_c) {
    // 4 slots x {A: 256x32 bf16 (16KB), B: 256x32 bf16 (16KB)} = 128 KiB
    __shared__ __hip_bfloat16 lds[4][2][BM * BK];

    const int tid  = threadIdx.x;
    const int lane = tid & 63;
    const int w    = tid >> 6;          // 0..7
    const int wr   = w >> 2;            // 0..1 (M)
    const int wc   = w & 3;             // 0..3 (N)
    const int l15  = lane & 15, lhi = lane >> 4;

    // XCD-aware swizzle (nwg = 256, divisible by 8)
    int bid = blockIdx.x;
    int swz = (bid & 7) * 32 + (bid >> 3);
    const int bm = (swz >> 4) * BM;
    const int bn = (swz & 15) * BN;

    // Staging: thread loads 16B to linear LDS byte i*8192 + tid*16.
    // Source col-byte is inverse-swizzled: c' = c ^ ((row&6)<<3).
    const int srow  = tid >> 2;                                    // + i*128
    const int scole = (((tid & 3) * 16) ^ (((tid >> 2) & 6) << 3)) >> 1;

    // ds_read swizzled k-offset (bytes within 64B row); row&6 == l15&6.
    const int koff = (lhi * 16) ^ ((l15 & 6) << 3);

#define STAGE(s, kt)                                                            \
    do {                                                                        \
        _Pragma("unroll")                                                       \
        for (int i_ = 0; i_ < 2; ++i_)                                          \
            __builtin_amdgcn_global_load_lds(                                   \
                (const __attribute__((address_space(1))) unsigned*)(            \
                    A + (size_t)(bm + i_ * 128 + srow) * Kdim + (kt) + scole),  \
                (__attribute__((address_space(3))) unsigned*)(                  \
                    (char*)&lds[s][0][0] + i_ * 8192 + tid * 16), 16, 0, 0);    \
        _Pragma("unroll")                                                       \
        for (int i_ = 0; i_ < 2; ++i_)                                          \
            __builtin_amdgcn_global_load_lds(                                   \
                (const __attribute__((address_space(1))) unsigned*)(            \
                    B + (size_t)(bn + i_ * 128 + srow) * Kdim + (kt) + scole),  \
                (__attribute__((address_space(3))) unsigned*)(                  \
                    (char*)&lds[s][1][0] + i_ * 8192 + tid * 16), 16, 0, 0);    \
    } while (0)

    f32x4 acc[8][4];
#pragma unroll
    for (int a = 0; a < 8; ++a)
#pragma unroll
        for (int b = 0; b < 4; ++b)
            acc[a][b] = (f32x4){0.f, 0.f, 0.f, 0.f};

    // Prologue: stage slots 0,1,2; wait slot 0 (slots 1,2 = 8 loads may fly).
    STAGE(0, 0);
    STAGE(1, BK);
    STAGE(2, 2 * BK);
    asm volatile("s_waitcnt vmcnt(8)" ::: "memory");
    __builtin_amdgcn_s_barrier();
    __builtin_amdgcn_sched_barrier(0);

    for (int t = 0; t < NT; ++t) {
        if (t + 3 < NT) STAGE((t + 3) & 3, (t + 3) * BK);

        const char* As = (const char*)&lds[t & 3][0][0];
        const char* Bs = (const char*)&lds[t & 3][1][0];

        short8 bfr[4];
#pragma unroll
        for (int b = 0; b < 4; ++b)
            bfr[b] = *(const short8*)(Bs + (wc * 64 + b * 16 + l15) * 64 + koff);

        __builtin_amdgcn_s_setprio(1);
#pragma unroll
        for (int a = 0; a < 8; ++a) {
            short8 af = *(const short8*)(As + (wr * 128 + a * 16 + l15) * 64 + koff);
#pragma unroll
            for (int b = 0; b < 4; ++b)
                acc[a][b] = __builtin_amdgcn_mfma_f32_16x16x32_bf16(af, bfr[b], acc[a][b], 0, 0, 0);
        }
        __builtin_amdgcn_s_setprio(0);

        // Counted waits: slots t+2,t+3 (8 loads) may stay in flight; t+1 landed.
        if (t < NT - 3)       asm volatile("s_waitcnt vmcnt(8)" ::: "memory");
        else if (t == NT - 3) asm volatile("s_waitcnt vmcnt(4)" ::: "memory");
        else if (t == NT - 2) asm volatile("s_waitcnt vmcnt(0)" ::: "memory");
        if (t < NT - 1) {
            __builtin_amdgcn_s_barrier();
            __builtin_amdgcn_sched_barrier(0);
        }
    }
#undef STAGE

    // ---- fused LSTM epilogue (shuffle-free) ----
    const int j0 = ((bn + wc * 64) >> 6) * 16 + l15;
    const float bi  = b_i[j0];
    const float bf_ = b_f[j0];
    const float bg  = b_g[j0];
    const float bo  = b_o[j0];

#pragma unroll
    for (int a = 0; a < 8; ++a) {
        int mbase = bm + wr * 128 + a * 16 + lhi * 4;
#pragma unroll
        for (int r = 0; r < 4; ++r) {
            int m = mbase + r;
            float vi = acc[a][0][r] + bi;
            float vf = acc[a][1][r] + bf_;
            float vg = acc[a][2][r] + bg;
            float vo = acc[a][3][r] + bo;
            float it = sigmoid_(vi);
            float ft = sigmoid_(vf);
            float gt = tanh_(vg);
            float ot = sigmoid_(vo);
            float cp = c_prev[(size_t)m * Hdim + j0];
            float ct = ft * cp + it * gt;
            float ht = ot * tanh_(ct);
            out_h[(size_t)m * Hdim + j0] = ht;
            out_c[(size_t)m * Hdim + j0] = ct;
        }
    }
}

extern "C" void kernel_launch(void* const* d_in, const int* in_sizes, int n_in,
                              void* d_out, int out_size, void* d_ws, size_t ws_size,
                              hipStream_t stream) {
    const float* x_t    = (const float*)d_in[0];
    const float* h_prev = (const float*)d_in[1];
    const float* c_prev = (const float*)d_in[2];
    const float* W_xi   = (const float*)d_in[3];
    const float* W_hi   = (const float*)d_in[4];
    const float* b_i    = (const float*)d_in[5];
    const float* W_xf   = (const float*)d_in[6];
    const float* W_hf   = (const float*)d_in[7];
    const float* b_f    = (const float*)d_in[8];
    const float* W_xg   = (const float*)d_in[9];
    const float* W_hg   = (const float*)d_in[10];
    const float* b_g    = (const float*)d_in[11];
    const float* W_xo   = (const float*)d_in[12];
    const float* W_ho   = (const float*)d_in[13];
    const float* b_o    = (const float*)d_in[14];

    float* out_h = (float*)d_out;
    float* out_c = out_h + (size_t)Mdim * Hdim;

    __hip_bfloat16* Abf = (__hip_bfloat16*)d_ws;
    __hip_bfloat16* Bbf = Abf + (size_t)Mdim * Kdim;

    build_A<<<4096, 256, 0, stream>>>(x_t, h_prev, Abf);
    build_B<<<4096, 256, 0, stream>>>(W_xi, W_hi, W_xf, W_hf, W_xg, W_hg, W_xo, W_ho, Bbf);

    lstm_gemm<<<dim3((Mdim / BM) * (Ndim / BN)), 512, 0, stream>>>(
        Abf, Bbf, c_prev, b_i, b_f, b_g, b_o, out_h, out_c);
}

// Round 4
// 90.765 us; speedup vs baseline: 1.6823x; 1.0061x over previous
//
#include <hip/hip_runtime.h>
#include <hip/hip_bf16.h>

// LSTM cell fused: C = [x|h] @ [Wx|Wh]^T (gate-per-16col-fragment N layout).
// GEMM M=4096, N=4096, K=2048. 256x256 tile, BK=64 (2 K-halves of 32),
// 8 waves (2Mx4N), 8-phase-per-2-K-tiles schedule (T3+T4+T5) with
// counted vmcnt(4), XOR-swizzled LDS (T2), XCD swizzle (T1).

constexpr int Mdim = 4096;
constexpr int Ndim = 4096;
constexpr int Kdim = 2048;
constexpr int Hdim = 1024;
constexpr int BM = 256;
constexpr int BN = 256;
constexpr int BK = 64;
constexpr int NT = Kdim / BK;   // 32 K-tiles

using short8 = __attribute__((ext_vector_type(8))) short;
using f32x4  = __attribute__((ext_vector_type(4))) float;

__device__ __forceinline__ float sigmoid_(float x) {
    return 1.f / (1.f + __expf(-x));
}
__device__ __forceinline__ float tanh_(float x) {
    float e = __expf(2.f * x);
    return (e - 1.f) / (e + 1.f);
}

// ---- build A = [x | h] as bf16 [4096][2048] ----
__global__ void build_A(const float* __restrict__ x, const float* __restrict__ h,
                        __hip_bfloat16* __restrict__ A) {
    int idx = blockIdx.x * 256 + threadIdx.x;
    int row = idx >> 8;
    int c8  = (idx & 255) * 8;
    const float* src = (c8 < 1024) ? (x + (size_t)row * 1024 + c8)
                                   : (h + (size_t)row * 1024 + (c8 - 1024));
    float4 f0 = ((const float4*)src)[0];
    float4 f1 = ((const float4*)src)[1];
    union { short8 v; __hip_bfloat16 e[8]; } u;
    u.e[0] = __float2bfloat16(f0.x); u.e[1] = __float2bfloat16(f0.y);
    u.e[2] = __float2bfloat16(f0.z); u.e[3] = __float2bfloat16(f0.w);
    u.e[4] = __float2bfloat16(f1.x); u.e[5] = __float2bfloat16(f1.y);
    u.e[6] = __float2bfloat16(f1.z); u.e[7] = __float2bfloat16(f1.w);
    *(short8*)(A + (size_t)row * Kdim + c8) = u.v;
}

// ---- build B: row n -> gate g=(n>>4)&3, unit j=((n>>6)<<4)|(n&15) ----
__global__ void build_B(const float* __restrict__ Wxi, const float* __restrict__ Whi,
                        const float* __restrict__ Wxf, const float* __restrict__ Whf,
                        const float* __restrict__ Wxg, const float* __restrict__ Whg,
                        const float* __restrict__ Wxo, const float* __restrict__ Who,
                        __hip_bfloat16* __restrict__ B) {
    int idx = blockIdx.x * 256 + threadIdx.x;
    int n  = idx >> 8;
    int c8 = (idx & 255) * 8;
    int g = (n >> 4) & 3;
    int j = ((n >> 6) << 4) | (n & 15);
    const float* Wx = (g == 0) ? Wxi : (g == 1) ? Wxf : (g == 2) ? Wxg : Wxo;
    const float* Wh = (g == 0) ? Whi : (g == 1) ? Whf : (g == 2) ? Whg : Who;
    const float* src = (c8 < 1024) ? (Wx + (size_t)j * 1024 + c8)
                                   : (Wh + (size_t)j * 1024 + (c8 - 1024));
    float4 f0 = ((const float4*)src)[0];
    float4 f1 = ((const float4*)src)[1];
    union { short8 v; __hip_bfloat16 e[8]; } u;
    u.e[0] = __float2bfloat16(f0.x); u.e[1] = __float2bfloat16(f0.y);
    u.e[2] = __float2bfloat16(f0.z); u.e[3] = __float2bfloat16(f0.w);
    u.e[4] = __float2bfloat16(f1.x); u.e[5] = __float2bfloat16(f1.y);
    u.e[6] = __float2bfloat16(f1.z); u.e[7] = __float2bfloat16(f1.w);
    *(short8*)(B + (size_t)n * Kdim + c8) = u.v;
}

#define BAR()                                    \
    do {                                         \
        asm volatile("" ::: "memory");           \
        __builtin_amdgcn_s_barrier();            \
        __builtin_amdgcn_sched_barrier(0);       \
    } while (0)

// ---- fused GEMM + LSTM epilogue, 8-phase schedule ----
__launch_bounds__(512, 1)
__global__ void lstm_gemm(const __hip_bfloat16* __restrict__ A,
                          const __hip_bfloat16* __restrict__ B,
                          const float* __restrict__ c_prev,
                          const float* __restrict__ b_i, const float* __restrict__ b_f,
                          const float* __restrict__ b_g, const float* __restrict__ b_o,
                          float* __restrict__ out_h, float* __restrict__ out_c) {
    // [dbuf][A=0/B=1][khalf][256 rows x 32 cols bf16] = 4 x 16KB x 2 = 128 KiB
    __shared__ __hip_bfloat16 lds[2][2][2][256 * 32];

    const int tid  = threadIdx.x;
    const int lane = tid & 63;
    const int w    = tid >> 6;          // 0..7
    const int wr   = w >> 2;            // 0..1 (M)
    const int wc   = w & 3;             // 0..3 (N)
    const int l15  = lane & 15, lhi = lane >> 4;

    // XCD-aware swizzle (nwg = 256, divisible by 8)
    int bid = blockIdx.x;
    int swz = (bid & 7) * 32 + (bid >> 3);
    const int bm = (swz >> 4) * BM;
    const int bn = (swz & 15) * BN;

    // Staging: thread loads 16B to linear LDS byte i*8192 + tid*16 of a region.
    // Source col-byte is inverse-swizzled: c' = c ^ ((row&6)<<3)  (64 B rows).
    const int srow  = tid >> 2;                                    // + i*128
    const int scole = (((tid & 3) * 16) ^ (((tid >> 2) & 6) << 3)) >> 1;

    // ds_read swizzled k-offset (bytes within 64 B row); row&6 == l15&6.
    const int koff = (lhi * 16) ^ ((l15 & 6) << 3);

    // stage one half-tile region (2 x global_load_lds per thread)
#define STG(dstbase, srcptr, growbase, kcol)                                    \
    do {                                                                        \
        _Pragma("unroll")                                                       \
        for (int i_ = 0; i_ < 2; ++i_)                                          \
            __builtin_amdgcn_global_load_lds(                                   \
                (const __attribute__((address_space(1))) unsigned*)(            \
                    (srcptr) + (size_t)((growbase) + i_ * 128 + srow) * Kdim    \
                    + (kcol) + scole),                                          \
                (__attribute__((address_space(3))) unsigned*)(                  \
                    (char*)(dstbase) + i_ * 8192 + tid * 16), 16, 0, 0);        \
    } while (0)

#define RDA(d, kk, a) (*(const short8*)((const char*)&lds[d][0][kk][0] + \
                        (wr * 128 + (a) * 16 + l15) * 64 + koff))
#define RDB(d, kk, b) (*(const short8*)((const char*)&lds[d][1][kk][0] + \
                        (wc * 64 + (b) * 16 + l15) * 64 + koff))

    f32x4 acc[8][4];
#pragma unroll
    for (int a = 0; a < 8; ++a)
#pragma unroll
        for (int b = 0; b < 4; ++b)
            acc[a][b] = (f32x4){0.f, 0.f, 0.f, 0.f};

    // ---- prologue: tile0 all 4 halves, tile1 kh0 halves; drain tile0 ----
    STG(&lds[0][0][0][0], A, bm, 0);        // A kh0 (t0)
    STG(&lds[0][1][0][0], B, bn, 0);        // B kh0 (t0)
    STG(&lds[0][0][1][0], A, bm, 32);       // A kh1 (t0)
    STG(&lds[0][1][1][0], B, bn, 32);       // B kh1 (t0)
    STG(&lds[1][0][0][0], A, bm, 64);       // A kh0 (t1)
    STG(&lds[1][1][0][0], B, bn, 64);       // B kh0 (t1)
    asm volatile("s_waitcnt vmcnt(4)" ::: "memory");  // tile0 landed; t1-kh0 in flight
    BAR();

    for (int t = 0; t < NT; ++t) {
        const int d = t & 1;

        // ---------- phase 1: kk0, a0-3 ----------
        short8 af0 = RDA(d, 0, 0), af1 = RDA(d, 0, 1), af2 = RDA(d, 0, 2), af3 = RDA(d, 0, 3);
        short8 bf0[4];
#pragma unroll
        for (int b = 0; b < 4; ++b) bf0[b] = RDB(d, 0, b);
        if (t + 1 < NT) {   // stage kh1 of tile t+1 into other dbuf
            STG(&lds[d ^ 1][0][1][0], A, bm, (t + 1) * BK + 32);
            STG(&lds[d ^ 1][1][1][0], B, bn, (t + 1) * BK + 32);
        }
        BAR();
        __builtin_amdgcn_s_setprio(1);
#pragma unroll
        for (int b = 0; b < 4; ++b) {
            acc[0][b] = __builtin_amdgcn_mfma_f32_16x16x32_bf16(af0, bf0[b], acc[0][b], 0, 0, 0);
            acc[1][b] = __builtin_amdgcn_mfma_f32_16x16x32_bf16(af1, bf0[b], acc[1][b], 0, 0, 0);
            acc[2][b] = __builtin_amdgcn_mfma_f32_16x16x32_bf16(af2, bf0[b], acc[2][b], 0, 0, 0);
            acc[3][b] = __builtin_amdgcn_mfma_f32_16x16x32_bf16(af3, bf0[b], acc[3][b], 0, 0, 0);
        }
        __builtin_amdgcn_s_setprio(0);
        BAR();

        // ---------- phase 2: kk0, a4-7 ----------
        short8 af4 = RDA(d, 0, 4), af5 = RDA(d, 0, 5), af6 = RDA(d, 0, 6), af7 = RDA(d, 0, 7);
        BAR();
        __builtin_amdgcn_s_setprio(1);
#pragma unroll
        for (int b = 0; b < 4; ++b) {
            acc[4][b] = __builtin_amdgcn_mfma_f32_16x16x32_bf16(af4, bf0[b], acc[4][b], 0, 0, 0);
            acc[5][b] = __builtin_amdgcn_mfma_f32_16x16x32_bf16(af5, bf0[b], acc[5][b], 0, 0, 0);
            acc[6][b] = __builtin_amdgcn_mfma_f32_16x16x32_bf16(af6, bf0[b], acc[6][b], 0, 0, 0);
            acc[7][b] = __builtin_amdgcn_mfma_f32_16x16x32_bf16(af7, bf0[b], acc[7][b], 0, 0, 0);
        }
        __builtin_amdgcn_s_setprio(0);
        BAR();

        // ---------- phase 3: kk1, a0-3 ----------
        af0 = RDA(d, 1, 0); af1 = RDA(d, 1, 1); af2 = RDA(d, 1, 2); af3 = RDA(d, 1, 3);
        short8 bf1[4];
#pragma unroll
        for (int b = 0; b < 4; ++b) bf1[b] = RDB(d, 1, b);
        if (t + 2 < NT)     // stage kh0-A of tile t+2 into THIS dbuf (kh0 reads done)
            STG(&lds[d][0][0][0], A, bm, (t + 2) * BK);
        BAR();
        __builtin_amdgcn_s_setprio(1);
#pragma unroll
        for (int b = 0; b < 4; ++b) {
            acc[0][b] = __builtin_amdgcn_mfma_f32_16x16x32_bf16(af0, bf1[b], acc[0][b], 0, 0, 0);
            acc[1][b] = __builtin_amdgcn_mfma_f32_16x16x32_bf16(af1, bf1[b], acc[1][b], 0, 0, 0);
            acc[2][b] = __builtin_amdgcn_mfma_f32_16x16x32_bf16(af2, bf1[b], acc[2][b], 0, 0, 0);
            acc[3][b] = __builtin_amdgcn_mfma_f32_16x16x32_bf16(af3, bf1[b], acc[3][b], 0, 0, 0);
        }
        __builtin_amdgcn_s_setprio(0);
        BAR();

        // ---------- phase 4: kk1, a4-7 ----------
        af4 = RDA(d, 1, 4); af5 = RDA(d, 1, 5); af6 = RDA(d, 1, 6); af7 = RDA(d, 1, 7);
        if (t + 2 < NT)     // stage kh0-B of tile t+2 into THIS dbuf
            STG(&lds[d][1][0][0], B, bn, (t + 2) * BK);
        BAR();
        __builtin_amdgcn_s_setprio(1);
#pragma unroll
        for (int b = 0; b < 4; ++b) {
            acc[4][b] = __builtin_amdgcn_mfma_f32_16x16x32_bf16(af4, bf1[b], acc[4][b], 0, 0, 0);
            acc[5][b] = __builtin_amdgcn_mfma_f32_16x16x32_bf16(af5, bf1[b], acc[5][b], 0, 0, 0);
            acc[6][b] = __builtin_amdgcn_mfma_f32_16x16x32_bf16(af6, bf1[b], acc[6][b], 0, 0, 0);
            acc[7][b] = __builtin_amdgcn_mfma_f32_16x16x32_bf16(af7, bf1[b], acc[7][b], 0, 0, 0);
        }
        __builtin_amdgcn_s_setprio(0);
        // tile-end counted wait: keep kh0(t+2)'s 4 loads in flight
        if (t < NT - 2)       asm volatile("s_waitcnt vmcnt(4)" ::: "memory");
        else if (t == NT - 2) asm volatile("s_waitcnt vmcnt(0)" ::: "memory");
        BAR();
    }
#undef STG
#undef RDA
#undef RDB

    // ---- fused LSTM epilogue (shuffle-free) ----
    const int j0 = ((bn + wc * 64) >> 6) * 16 + l15;
    const float bi  = b_i[j0];
    const float bf_ = b_f[j0];
    const float bg  = b_g[j0];
    const float bo  = b_o[j0];

#pragma unroll
    for (int a = 0; a < 8; ++a) {
        int mbase = bm + wr * 128 + a * 16 + lhi * 4;
#pragma unroll
        for (int r = 0; r < 4; ++r) {
            int m = mbase + r;
            float vi = acc[a][0][r] + bi;
            float vf = acc[a][1][r] + bf_;
            float vg = acc[a][2][r] + bg;
            float vo = acc[a][3][r] + bo;
            float it = sigmoid_(vi);
            float ft = sigmoid_(vf);
            float gt = tanh_(vg);
            float ot = sigmoid_(vo);
            float cp = c_prev[(size_t)m * Hdim + j0];
            float ct = ft * cp + it * gt;
            float ht = ot * tanh_(ct);
            out_h[(size_t)m * Hdim + j0] = ht;
            out_c[(size_t)m * Hdim + j0] = ct;
        }
    }
}

extern "C" void kernel_launch(void* const* d_in, const int* in_sizes, int n_in,
                              void* d_out, int out_size, void* d_ws, size_t ws_size,
                              hipStream_t stream) {
    const float* x_t    = (const float*)d_in[0];
    const float* h_prev = (const float*)d_in[1];
    const float* c_prev = (const float*)d_in[2];
    const float* W_xi   = (const float*)d_in[3];
    const float* W_hi   = (const float*)d_in[4];
    const float* b_i    = (const float*)d_in[5];
    const float* W_xf   = (const float*)d_in[6];
    const float* W_hf   = (const float*)d_in[7];
    const float* b_f    = (const float*)d_in[8];
    const float* W_xg   = (const float*)d_in[9];
    const float* W_hg   = (const float*)d_in[10];
    const float* b_g    = (const float*)d_in[11];
    const float* W_xo   = (const float*)d_in[12];
    const float* W_ho   = (const float*)d_in[13];
    const float* b_o    = (const float*)d_in[14];

    float* out_h = (float*)d_out;
    float* out_c = out_h + (size_t)Mdim * Hdim;

    __hip_bfloat16* Abf = (__hip_bfloat16*)d_ws;
    __hip_bfloat16* Bbf = Abf + (size_t)Mdim * Kdim;

    build_A<<<4096, 256, 0, stream>>>(x_t, h_prev, Abf);
    build_B<<<4096, 256, 0, stream>>>(W_xi, W_hi, W_xf, W_hf, W_xg, W_hg, W_xo, W_ho, Bbf);

    lstm_gemm<<<dim3((Mdim / BM) * (Ndim / BN)), 512, 0, stream>>>(
        Abf, Bbf, c_prev, b_i, b_f, b_g, b_o, out_h, out_c);
}

// Round 5
// 90.202 us; speedup vs baseline: 1.6927x; 1.0062x over previous
//
#include <hip/hip_runtime.h>
#include <hip/hip_bf16.h>

// LSTM cell fused: C = [x|h] @ [Wx|Wh]^T (gate-per-16col-fragment N layout).
// GEMM M=4096, N=4096, K=2048. 256x256 tile, BK=64 (2 K-halves of 32),
// 8 waves (2Mx4N), 4-phase-per-K-tile schedule (T3+T4+T5) with counted
// vmcnt(4), XOR-swizzled LDS (T2), XCD swizzle (T1).
// R5: bare s_barrier (no memory-clobber asm, no sched_barrier) — m201 idiom;
// previous BAR() provoked conservative waitcnt drains (m141 effect).

constexpr int Mdim = 4096;
constexpr int Ndim = 4096;
constexpr int Kdim = 2048;
constexpr int Hdim = 1024;
constexpr int BM = 256;
constexpr int BN = 256;
constexpr int BK = 64;
constexpr int NT = Kdim / BK;   // 32 K-tiles

using short8 = __attribute__((ext_vector_type(8))) short;
using f32x4  = __attribute__((ext_vector_type(4))) float;

__device__ __forceinline__ float sigmoid_(float x) {
    return 1.f / (1.f + __expf(-x));
}
__device__ __forceinline__ float tanh_(float x) {
    float e = __expf(2.f * x);
    return (e - 1.f) / (e + 1.f);
}

// ---- build A = [x | h] as bf16 [4096][2048] ----
__global__ void build_A(const float* __restrict__ x, const float* __restrict__ h,
                        __hip_bfloat16* __restrict__ A) {
    int idx = blockIdx.x * 256 + threadIdx.x;
    int row = idx >> 8;
    int c8  = (idx & 255) * 8;
    const float* src = (c8 < 1024) ? (x + (size_t)row * 1024 + c8)
                                   : (h + (size_t)row * 1024 + (c8 - 1024));
    float4 f0 = ((const float4*)src)[0];
    float4 f1 = ((const float4*)src)[1];
    union { short8 v; __hip_bfloat16 e[8]; } u;
    u.e[0] = __float2bfloat16(f0.x); u.e[1] = __float2bfloat16(f0.y);
    u.e[2] = __float2bfloat16(f0.z); u.e[3] = __float2bfloat16(f0.w);
    u.e[4] = __float2bfloat16(f1.x); u.e[5] = __float2bfloat16(f1.y);
    u.e[6] = __float2bfloat16(f1.z); u.e[7] = __float2bfloat16(f1.w);
    *(short8*)(A + (size_t)row * Kdim + c8) = u.v;
}

// ---- build B: row n -> gate g=(n>>4)&3, unit j=((n>>6)<<4)|(n&15) ----
__global__ void build_B(const float* __restrict__ Wxi, const float* __restrict__ Whi,
                        const float* __restrict__ Wxf, const float* __restrict__ Whf,
                        const float* __restrict__ Wxg, const float* __restrict__ Whg,
                        const float* __restrict__ Wxo, const float* __restrict__ Who,
                        __hip_bfloat16* __restrict__ B) {
    int idx = blockIdx.x * 256 + threadIdx.x;
    int n  = idx >> 8;
    int c8 = (idx & 255) * 8;
    int g = (n >> 4) & 3;
    int j = ((n >> 6) << 4) | (n & 15);
    const float* Wx = (g == 0) ? Wxi : (g == 1) ? Wxf : (g == 2) ? Wxg : Wxo;
    const float* Wh = (g == 0) ? Whi : (g == 1) ? Whf : (g == 2) ? Whg : Who;
    const float* src = (c8 < 1024) ? (Wx + (size_t)j * 1024 + c8)
                                   : (Wh + (size_t)j * 1024 + (c8 - 1024));
    float4 f0 = ((const float4*)src)[0];
    float4 f1 = ((const float4*)src)[1];
    union { short8 v; __hip_bfloat16 e[8]; } u;
    u.e[0] = __float2bfloat16(f0.x); u.e[1] = __float2bfloat16(f0.y);
    u.e[2] = __float2bfloat16(f0.z); u.e[3] = __float2bfloat16(f0.w);
    u.e[4] = __float2bfloat16(f1.x); u.e[5] = __float2bfloat16(f1.y);
    u.e[6] = __float2bfloat16(f1.z); u.e[7] = __float2bfloat16(f1.w);
    *(short8*)(B + (size_t)n * Kdim + c8) = u.v;
}

#define BAR() __builtin_amdgcn_s_barrier()

// ---- fused GEMM + LSTM epilogue, 4-phase-per-tile schedule ----
__launch_bounds__(512, 1)
__global__ void lstm_gemm(const __hip_bfloat16* __restrict__ A,
                          const __hip_bfloat16* __restrict__ B,
                          const float* __restrict__ c_prev,
                          const float* __restrict__ b_i, const float* __restrict__ b_f,
                          const float* __restrict__ b_g, const float* __restrict__ b_o,
                          float* __restrict__ out_h, float* __restrict__ out_c) {
    // [dbuf][A=0/B=1][khalf][256 rows x 32 cols bf16] = 4 x 16KB x 2 = 128 KiB
    __shared__ __hip_bfloat16 lds[2][2][2][256 * 32];

    const int tid  = threadIdx.x;
    const int lane = tid & 63;
    const int w    = tid >> 6;          // 0..7
    const int wr   = w >> 2;            // 0..1 (M)
    const int wc   = w & 3;             // 0..3 (N)
    const int l15  = lane & 15, lhi = lane >> 4;

    // XCD-aware swizzle (nwg = 256, divisible by 8)
    int bid = blockIdx.x;
    int swz = (bid & 7) * 32 + (bid >> 3);
    const int bm = (swz >> 4) * BM;
    const int bn = (swz & 15) * BN;

    // Staging: thread loads 16B to linear LDS byte i*8192 + tid*16 of a region.
    // Source col-byte is inverse-swizzled: c' = c ^ ((row&6)<<3)  (64 B rows).
    const int srow  = tid >> 2;                                    // + i*128
    const int scole = (((tid & 3) * 16) ^ (((tid >> 2) & 6) << 3)) >> 1;

    // ds_read swizzled k-offset (bytes within 64 B row); row&6 == l15&6.
    const int koff = (lhi * 16) ^ ((l15 & 6) << 3);

    // stage one half-tile region (2 x global_load_lds per thread)
#define STG(dstbase, srcptr, growbase, kcol)                                    \
    do {                                                                        \
        _Pragma("unroll")                                                       \
        for (int i_ = 0; i_ < 2; ++i_)                                          \
            __builtin_amdgcn_global_load_lds(                                   \
                (const __attribute__((address_space(1))) unsigned*)(            \
                    (srcptr) + (size_t)((growbase) + i_ * 128 + srow) * Kdim    \
                    + (kcol) + scole),                                          \
                (__attribute__((address_space(3))) unsigned*)(                  \
                    (char*)(dstbase) + i_ * 8192 + tid * 16), 16, 0, 0);        \
    } while (0)

#define RDA(d, kk, a) (*(const short8*)((const char*)&lds[d][0][kk][0] + \
                        (wr * 128 + (a) * 16 + l15) * 64 + koff))
#define RDB(d, kk, b) (*(const short8*)((const char*)&lds[d][1][kk][0] + \
                        (wc * 64 + (b) * 16 + l15) * 64 + koff))

    f32x4 acc[8][4];
#pragma unroll
    for (int a = 0; a < 8; ++a)
#pragma unroll
        for (int b = 0; b < 4; ++b)
            acc[a][b] = (f32x4){0.f, 0.f, 0.f, 0.f};

    // ---- prologue: tile0 all 4 halves, tile1 kh0 halves; drain tile0 ----
    STG(&lds[0][0][0][0], A, bm, 0);        // A kh0 (t0)
    STG(&lds[0][1][0][0], B, bn, 0);        // B kh0 (t0)
    STG(&lds[0][0][1][0], A, bm, 32);       // A kh1 (t0)
    STG(&lds[0][1][1][0], B, bn, 32);       // B kh1 (t0)
    STG(&lds[1][0][0][0], A, bm, 64);       // A kh0 (t1)
    STG(&lds[1][1][0][0], B, bn, 64);       // B kh0 (t1)
    asm volatile("s_waitcnt vmcnt(4)" ::: "memory");  // tile0 landed; t1-kh0 in flight
    BAR();

    for (int t = 0; t < NT; ++t) {
        const int d = t & 1;

        // ---------- phase 1: kk0, a0-3 ----------
        short8 af0 = RDA(d, 0, 0), af1 = RDA(d, 0, 1), af2 = RDA(d, 0, 2), af3 = RDA(d, 0, 3);
        short8 bf0[4];
#pragma unroll
        for (int b = 0; b < 4; ++b) bf0[b] = RDB(d, 0, b);
        if (t + 1 < NT) {   // stage kh1 of tile t+1 into other dbuf
            STG(&lds[d ^ 1][0][1][0], A, bm, (t + 1) * BK + 32);
            STG(&lds[d ^ 1][1][1][0], B, bn, (t + 1) * BK + 32);
        }
        BAR();
        __builtin_amdgcn_s_setprio(1);
#pragma unroll
        for (int b = 0; b < 4; ++b) {
            acc[0][b] = __builtin_amdgcn_mfma_f32_16x16x32_bf16(af0, bf0[b], acc[0][b], 0, 0, 0);
            acc[1][b] = __builtin_amdgcn_mfma_f32_16x16x32_bf16(af1, bf0[b], acc[1][b], 0, 0, 0);
            acc[2][b] = __builtin_amdgcn_mfma_f32_16x16x32_bf16(af2, bf0[b], acc[2][b], 0, 0, 0);
            acc[3][b] = __builtin_amdgcn_mfma_f32_16x16x32_bf16(af3, bf0[b], acc[3][b], 0, 0, 0);
        }
        __builtin_amdgcn_s_setprio(0);
        BAR();

        // ---------- phase 2: kk0, a4-7 ----------
        short8 af4 = RDA(d, 0, 4), af5 = RDA(d, 0, 5), af6 = RDA(d, 0, 6), af7 = RDA(d, 0, 7);
        BAR();
        __builtin_amdgcn_s_setprio(1);
#pragma unroll
        for (int b = 0; b < 4; ++b) {
            acc[4][b] = __builtin_amdgcn_mfma_f32_16x16x32_bf16(af4, bf0[b], acc[4][b], 0, 0, 0);
            acc[5][b] = __builtin_amdgcn_mfma_f32_16x16x32_bf16(af5, bf0[b], acc[5][b], 0, 0, 0);
            acc[6][b] = __builtin_amdgcn_mfma_f32_16x16x32_bf16(af6, bf0[b], acc[6][b], 0, 0, 0);
            acc[7][b] = __builtin_amdgcn_mfma_f32_16x16x32_bf16(af7, bf0[b], acc[7][b], 0, 0, 0);
        }
        __builtin_amdgcn_s_setprio(0);
        BAR();

        // ---------- phase 3: kk1, a0-3 ----------
        af0 = RDA(d, 1, 0); af1 = RDA(d, 1, 1); af2 = RDA(d, 1, 2); af3 = RDA(d, 1, 3);
        short8 bf1[4];
#pragma unroll
        for (int b = 0; b < 4; ++b) bf1[b] = RDB(d, 1, b);
        if (t + 2 < NT)     // stage kh0-A of tile t+2 into THIS dbuf (kh0 reads done)
            STG(&lds[d][0][0][0], A, bm, (t + 2) * BK);
        BAR();
        __builtin_amdgcn_s_setprio(1);
#pragma unroll
        for (int b = 0; b < 4; ++b) {
            acc[0][b] = __builtin_amdgcn_mfma_f32_16x16x32_bf16(af0, bf1[b], acc[0][b], 0, 0, 0);
            acc[1][b] = __builtin_amdgcn_mfma_f32_16x16x32_bf16(af1, bf1[b], acc[1][b], 0, 0, 0);
            acc[2][b] = __builtin_amdgcn_mfma_f32_16x16x32_bf16(af2, bf1[b], acc[2][b], 0, 0, 0);
            acc[3][b] = __builtin_amdgcn_mfma_f32_16x16x32_bf16(af3, bf1[b], acc[3][b], 0, 0, 0);
        }
        __builtin_amdgcn_s_setprio(0);
        BAR();

        // ---------- phase 4: kk1, a4-7 ----------
        af4 = RDA(d, 1, 4); af5 = RDA(d, 1, 5); af6 = RDA(d, 1, 6); af7 = RDA(d, 1, 7);
        if (t + 2 < NT)     // stage kh0-B of tile t+2 into THIS dbuf
            STG(&lds[d][1][0][0], B, bn, (t + 2) * BK);
        BAR();
        __builtin_amdgcn_s_setprio(1);
#pragma unroll
        for (int b = 0; b < 4; ++b) {
            acc[4][b] = __builtin_amdgcn_mfma_f32_16x16x32_bf16(af4, bf1[b], acc[4][b], 0, 0, 0);
            acc[5][b] = __builtin_amdgcn_mfma_f32_16x16x32_bf16(af5, bf1[b], acc[5][b], 0, 0, 0);
            acc[6][b] = __builtin_amdgcn_mfma_f32_16x16x32_bf16(af6, bf1[b], acc[6][b], 0, 0, 0);
            acc[7][b] = __builtin_amdgcn_mfma_f32_16x16x32_bf16(af7, bf1[b], acc[7][b], 0, 0, 0);
        }
        __builtin_amdgcn_s_setprio(0);
        // tile-end counted wait: keep kh0(t+2)'s 4 loads in flight
        if (t < NT - 2)       asm volatile("s_waitcnt vmcnt(4)" ::: "memory");
        else if (t == NT - 2) asm volatile("s_waitcnt vmcnt(0)" ::: "memory");
        BAR();
    }
#undef STG
#undef RDA
#undef RDB

    // ---- fused LSTM epilogue (shuffle-free) ----
    const int j0 = ((bn + wc * 64) >> 6) * 16 + l15;
    const float bi  = b_i[j0];
    const float bf_ = b_f[j0];
    const float bg  = b_g[j0];
    const float bo  = b_o[j0];

#pragma unroll
    for (int a = 0; a < 8; ++a) {
        int mbase = bm + wr * 128 + a * 16 + lhi * 4;
#pragma unroll
        for (int r = 0; r < 4; ++r) {
            int m = mbase + r;
            float vi = acc[a][0][r] + bi;
            float vf = acc[a][1][r] + bf_;
            float vg = acc[a][2][r] + bg;
            float vo = acc[a][3][r] + bo;
            float it = sigmoid_(vi);
            float ft = sigmoid_(vf);
            float gt = tanh_(vg);
            float ot = sigmoid_(vo);
            float cp = c_prev[(size_t)m * Hdim + j0];
            float ct = ft * cp + it * gt;
            float ht = ot * tanh_(ct);
            out_h[(size_t)m * Hdim + j0] = ht;
            out_c[(size_t)m * Hdim + j0] = ct;
        }
    }
}

extern "C" void kernel_launch(void* const* d_in, const int* in_sizes, int n_in,
                              void* d_out, int out_size, void* d_ws, size_t ws_size,
                              hipStream_t stream) {
    const float* x_t    = (const float*)d_in[0];
    const float* h_prev = (const float*)d_in[1];
    const float* c_prev = (const float*)d_in[2];
    const float* W_xi   = (const float*)d_in[3];
    const float* W_hi   = (const float*)d_in[4];
    const float* b_i    = (const float*)d_in[5];
    const float* W_xf   = (const float*)d_in[6];
    const float* W_hf   = (const float*)d_in[7];
    const float* b_f    = (const float*)d_in[8];
    const float* W_xg   = (const float*)d_in[9];
    const float* W_hg   = (const float*)d_in[10];
    const float* b_g    = (const float*)d_in[11];
    const float* W_xo   = (const float*)d_in[12];
    const float* W_ho   = (const float*)d_in[13];
    const float* b_o    = (const float*)d_in[14];

    float* out_h = (float*)d_out;
    float* out_c = out_h + (size_t)Mdim * Hdim;

    __hip_bfloat16* Abf = (__hip_bfloat16*)d_ws;
    __hip_bfloat16* Bbf = Abf + (size_t)Mdim * Kdim;

    build_A<<<4096, 256, 0, stream>>>(x_t, h_prev, Abf);
    build_B<<<4096, 256, 0, stream>>>(W_xi, W_hi, W_xf, W_hf, W_xg, W_hg, W_xo, W_ho, Bbf);

    lstm_gemm<<<dim3((Mdim / BM) * (Ndim / BN)), 512, 0, stream>>>(
        Abf, Bbf, c_prev, b_i, b_f, b_g, b_o, out_h, out_c);
}

// Round 6
// 86.090 us; speedup vs baseline: 1.7736x; 1.0478x over previous
//
#include <hip/hip_runtime.h>
#include <hip/hip_bf16.h>

// LSTM cell fused: C = [x|h] @ [Wx|Wh]^T (gate-per-16col-fragment N layout).
// GEMM M=4096, N=4096, K=2048. 256x256 tile, BK=64, 8 waves (2Mx4N).
// R6: m201-style fine interleave — 4 phases/tile, 2 global_load_lds EVERY
// phase, 16 MFMA/phase (b-major quadrants), counted vmcnt(4)@P2 / vmcnt(2)@P4,
// M/N-half LDS regions [dbuf][mat][half][128x64] with XOR swizzle
// byte ^= (row&7)<<4 (conflict-free ds_read_b128), linear gll dest +
// pre-permuted global source.

constexpr int Mdim = 4096;
constexpr int Ndim = 4096;
constexpr int Kdim = 2048;
constexpr int Hdim = 1024;
constexpr int BM = 256;
constexpr int BN = 256;
constexpr int BK = 64;
constexpr int NT = Kdim / BK;   // 32 K-tiles

using short8 = __attribute__((ext_vector_type(8))) short;
using f32x4  = __attribute__((ext_vector_type(4))) float;

__device__ __forceinline__ float sigmoid_(float x) {
    return 1.f / (1.f + __expf(-x));
}
__device__ __forceinline__ float tanh_(float x) {
    float e = __expf(2.f * x);
    return (e - 1.f) / (e + 1.f);
}

// ---- build A = [x | h] as bf16 [4096][2048] ----
__global__ void build_A(const float* __restrict__ x, const float* __restrict__ h,
                        __hip_bfloat16* __restrict__ A) {
    int idx = blockIdx.x * 256 + threadIdx.x;
    int row = idx >> 8;
    int c8  = (idx & 255) * 8;
    const float* src = (c8 < 1024) ? (x + (size_t)row * 1024 + c8)
                                   : (h + (size_t)row * 1024 + (c8 - 1024));
    float4 f0 = ((const float4*)src)[0];
    float4 f1 = ((const float4*)src)[1];
    union { short8 v; __hip_bfloat16 e[8]; } u;
    u.e[0] = __float2bfloat16(f0.x); u.e[1] = __float2bfloat16(f0.y);
    u.e[2] = __float2bfloat16(f0.z); u.e[3] = __float2bfloat16(f0.w);
    u.e[4] = __float2bfloat16(f1.x); u.e[5] = __float2bfloat16(f1.y);
    u.e[6] = __float2bfloat16(f1.z); u.e[7] = __float2bfloat16(f1.w);
    *(short8*)(A + (size_t)row * Kdim + c8) = u.v;
}

// ---- build B: row n -> gate g=(n>>4)&3, unit j=((n>>6)<<4)|(n&15) ----
__global__ void build_B(const float* __restrict__ Wxi, const float* __restrict__ Whi,
                        const float* __restrict__ Wxf, const float* __restrict__ Whf,
                        const float* __restrict__ Wxg, const float* __restrict__ Whg,
                        const float* __restrict__ Wxo, const float* __restrict__ Who,
                        __hip_bfloat16* __restrict__ B) {
    int idx = blockIdx.x * 256 + threadIdx.x;
    int n  = idx >> 8;
    int c8 = (idx & 255) * 8;
    int g = (n >> 4) & 3;
    int j = ((n >> 6) << 4) | (n & 15);
    const float* Wx = (g == 0) ? Wxi : (g == 1) ? Wxf : (g == 2) ? Wxg : Wxo;
    const float* Wh = (g == 0) ? Whi : (g == 1) ? Whf : (g == 2) ? Whg : Who;
    const float* src = (c8 < 1024) ? (Wx + (size_t)j * 1024 + c8)
                                   : (Wh + (size_t)j * 1024 + (c8 - 1024));
    float4 f0 = ((const float4*)src)[0];
    float4 f1 = ((const float4*)src)[1];
    union { short8 v; __hip_bfloat16 e[8]; } u;
    u.e[0] = __float2bfloat16(f0.x); u.e[1] = __float2bfloat16(f0.y);
    u.e[2] = __float2bfloat16(f0.z); u.e[3] = __float2bfloat16(f0.w);
    u.e[4] = __float2bfloat16(f1.x); u.e[5] = __float2bfloat16(f1.y);
    u.e[6] = __float2bfloat16(f1.z); u.e[7] = __float2bfloat16(f1.w);
    *(short8*)(B + (size_t)n * Kdim + c8) = u.v;
}

#define BAR() __builtin_amdgcn_s_barrier()
#define RD(p) (*(const short8*)(p))

// ---- fused GEMM + LSTM epilogue ----
__launch_bounds__(512, 2)
__global__ void lstm_gemm(const __hip_bfloat16* __restrict__ A,
                          const __hip_bfloat16* __restrict__ B,
                          const float* __restrict__ c_prev,
                          const float* __restrict__ b_i, const float* __restrict__ b_f,
                          const float* __restrict__ b_g, const float* __restrict__ b_o,
                          float* __restrict__ out_h, float* __restrict__ out_c) {
    // [dbuf][A=0/B=1][half][128 rows x 64 cols bf16] = 8 regions x 16 KB = 128 KiB
    __shared__ __hip_bfloat16 lds[2][2][2][128 * 64];

    const int tid  = threadIdx.x;
    const int lane = tid & 63;
    const int w    = tid >> 6;          // 0..7
    const int wr   = w >> 2;            // 0..1 (M half)
    const int wc   = w & 3;             // 0..3 (N quarter)
    const int l15  = lane & 15, lhi = lane >> 4;

    // XCD-aware swizzle (nwg = 256, divisible by 8)
    int bid = blockIdx.x;
    int swz = (bid & 7) * 32 + (bid >> 3);
    const int bm = (swz >> 4) * BM;
    const int bn = (swz & 15) * BN;

    // Staging: thread writes LDS bytes [off + tid*16); LDS row = off/8192*64 + tid>>3,
    // chunk = tid&7. Source col pre-permuted: chunk_src = (tid&7) ^ ((tid>>3)&7).
    const int srow_  = tid >> 3;                                  // + 64*i per load
    const int schunk = ((tid & 7) ^ ((tid >> 3) & 7)) * 8;        // col element

    // ds_read swizzle: byte-in-row = (kk*64 + lhi*16) ^ ((row&7)<<4), row&7 == l15&7
    const int swz4 = (l15 & 7) << 4;
    const int kof0 = (lhi * 16) ^ swz4;
    const int kof1 = (64 + lhi * 16) ^ swz4;

#define STG1(dstbase, byteoff, srcptr, grow, kcol)                              \
    __builtin_amdgcn_global_load_lds(                                           \
        (const __attribute__((address_space(1))) unsigned*)(                    \
            (srcptr) + (size_t)((grow) + srow_) * Kdim + (kcol) + schunk),      \
        (__attribute__((address_space(3))) unsigned*)(                          \
            (char*)(dstbase) + (byteoff) + tid * 16), 16, 0, 0)

    f32x4 acc[8][4];
#pragma unroll
    for (int a = 0; a < 8; ++a)
#pragma unroll
        for (int b = 0; b < 4; ++b)
            acc[a][b] = (f32x4){0.f, 0.f, 0.f, 0.f};

    // ---- prologue: stage all 4 regions of tile 0 (8 loads), drain ----
    STG1(&lds[0][1][0][0], 0,    B, bn + 0,   0);
    STG1(&lds[0][1][0][0], 8192, B, bn + 64,  0);
    STG1(&lds[0][1][1][0], 0,    B, bn + 128, 0);
    STG1(&lds[0][1][1][0], 8192, B, bn + 192, 0);
    STG1(&lds[0][0][0][0], 0,    A, bm + 0,   0);
    STG1(&lds[0][0][1][0], 0,    A, bm + 128, 0);
    STG1(&lds[0][0][0][0], 8192, A, bm + 64,  0);
    STG1(&lds[0][0][1][0], 8192, A, bm + 192, 0);
    asm volatile("s_waitcnt vmcnt(0)" ::: "memory");
    BAR();

    for (int t = 0; t < NT; ++t) {
        const int d  = t & 1;
        const int kn = (t + 1) * BK;
        const char* Ab = (const char*)&lds[d][0][wr][0] + l15 * 128;
        const char* Bb = (const char*)&lds[d][1][wc >> 1][0] + ((wc & 1) * 64 + l15) * 128;

        short8 af[4][2];    // a0-3 in P1-P2, reused for a4-7 in P3-P4
        short8 bf01[2][2];  // lives P1 -> P4
        short8 bf23[2][2];  // lives P2 -> P3

        // ======== P1: read af03(8) + bf01(4); stage Bh0(t+1); mfma a0-3 x b0-1
#pragma unroll
        for (int a = 0; a < 4; ++a) {
            af[a][0] = RD(Ab + a * 2048 + kof0);
            af[a][1] = RD(Ab + a * 2048 + kof1);
        }
#pragma unroll
        for (int b = 0; b < 2; ++b) {
            bf01[b][0] = RD(Bb + b * 2048 + kof0);
            bf01[b][1] = RD(Bb + b * 2048 + kof1);
        }
        if (t + 1 < NT) {
            STG1(&lds[d ^ 1][1][0][0], 0,    B, bn + 0,  kn);
            STG1(&lds[d ^ 1][1][0][0], 8192, B, bn + 64, kn);
        }
        BAR();
        __builtin_amdgcn_s_setprio(1);
#pragma unroll
        for (int a = 0; a < 4; ++a)
#pragma unroll
            for (int b = 0; b < 2; ++b)
#pragma unroll
                for (int kk = 0; kk < 2; ++kk)
                    acc[a][b] = __builtin_amdgcn_mfma_f32_16x16x32_bf16(af[a][kk], bf01[b][kk], acc[a][b], 0, 0, 0);
        __builtin_amdgcn_s_setprio(0);
        BAR();

        // ======== P2: read bf23(4); stage Bh1(t+1); mfma a0-3 x b2-3
#pragma unroll
        for (int b = 0; b < 2; ++b) {
            bf23[b][0] = RD(Bb + (2 + b) * 2048 + kof0);
            bf23[b][1] = RD(Bb + (2 + b) * 2048 + kof1);
        }
        if (t + 1 < NT) {
            STG1(&lds[d ^ 1][1][1][0], 0,    B, bn + 128, kn);
            STG1(&lds[d ^ 1][1][1][0], 8192, B, bn + 192, kn);
        }
        BAR();
        __builtin_amdgcn_s_setprio(1);
#pragma unroll
        for (int a = 0; a < 4; ++a)
#pragma unroll
            for (int b = 0; b < 2; ++b)
#pragma unroll
                for (int kk = 0; kk < 2; ++kk)
                    acc[a][2 + b] = __builtin_amdgcn_mfma_f32_16x16x32_bf16(af[a][kk], bf23[b][kk], acc[a][2 + b], 0, 0, 0);
        __builtin_amdgcn_s_setprio(0);
        if (t < NT - 1) asm volatile("s_waitcnt vmcnt(4)" ::: "memory");
        else            asm volatile("s_waitcnt vmcnt(0)" ::: "memory");
        BAR();

        // ======== P3: read af47(8); stage A.i0(t+1); mfma a4-7 x b2-3
#pragma unroll
        for (int a = 0; a < 4; ++a) {
            af[a][0] = RD(Ab + (4 + a) * 2048 + kof0);
            af[a][1] = RD(Ab + (4 + a) * 2048 + kof1);
        }
        if (t + 1 < NT) {
            STG1(&lds[d ^ 1][0][0][0], 0, A, bm + 0,   kn);
            STG1(&lds[d ^ 1][0][1][0], 0, A, bm + 128, kn);
        }
        BAR();
        __builtin_amdgcn_s_setprio(1);
#pragma unroll
        for (int a = 0; a < 4; ++a)
#pragma unroll
            for (int b = 0; b < 2; ++b)
#pragma unroll
                for (int kk = 0; kk < 2; ++kk)
                    acc[4 + a][2 + b] = __builtin_amdgcn_mfma_f32_16x16x32_bf16(af[a][kk], bf23[b][kk], acc[4 + a][2 + b], 0, 0, 0);
        __builtin_amdgcn_s_setprio(0);
        BAR();

        // ======== P4: no reads; stage A.i1(t+1); mfma a4-7 x b0-1
        if (t + 1 < NT) {
            STG1(&lds[d ^ 1][0][0][0], 8192, A, bm + 64,  kn);
            STG1(&lds[d ^ 1][0][1][0], 8192, A, bm + 192, kn);
        }
        BAR();
        __builtin_amdgcn_s_setprio(1);
#pragma unroll
        for (int a = 0; a < 4; ++a)
#pragma unroll
            for (int b = 0; b < 2; ++b)
#pragma unroll
                for (int kk = 0; kk < 2; ++kk)
                    acc[4 + a][b] = __builtin_amdgcn_mfma_f32_16x16x32_bf16(af[a][kk], bf01[b][kk], acc[4 + a][b], 0, 0, 0);
        __builtin_amdgcn_s_setprio(0);
        if (t < NT - 1) asm volatile("s_waitcnt vmcnt(2)" ::: "memory");
        BAR();
    }
#undef STG1

    // ---- fused LSTM epilogue (shuffle-free) ----
    const int j0 = ((bn + wc * 64) >> 6) * 16 + l15;
    const float bi  = b_i[j0];
    const float bf_ = b_f[j0];
    const float bg  = b_g[j0];
    const float bo  = b_o[j0];

#pragma unroll
    for (int a = 0; a < 8; ++a) {
        int mbase = bm + wr * 128 + a * 16 + lhi * 4;
#pragma unroll
        for (int r = 0; r < 4; ++r) {
            int m = mbase + r;
            float vi = acc[a][0][r] + bi;
            float vf = acc[a][1][r] + bf_;
            float vg = acc[a][2][r] + bg;
            float vo = acc[a][3][r] + bo;
            float it = sigmoid_(vi);
            float ft = sigmoid_(vf);
            float gt = tanh_(vg);
            float ot = sigmoid_(vo);
            float cp = c_prev[(size_t)m * Hdim + j0];
            float ct = ft * cp + it * gt;
            float ht = ot * tanh_(ct);
            out_h[(size_t)m * Hdim + j0] = ht;
            out_c[(size_t)m * Hdim + j0] = ct;
        }
    }
}

extern "C" void kernel_launch(void* const* d_in, const int* in_sizes, int n_in,
                              void* d_out, int out_size, void* d_ws, size_t ws_size,
                              hipStream_t stream) {
    const float* x_t    = (const float*)d_in[0];
    const float* h_prev = (const float*)d_in[1];
    const float* c_prev = (const float*)d_in[2];
    const float* W_xi   = (const float*)d_in[3];
    const float* W_hi   = (const float*)d_in[4];
    const float* b_i    = (const float*)d_in[5];
    const float* W_xf   = (const float*)d_in[6];
    const float* W_hf   = (const float*)d_in[7];
    const float* b_f    = (const float*)d_in[8];
    const float* W_xg   = (const float*)d_in[9];
    const float* W_hg   = (const float*)d_in[10];
    const float* b_g    = (const float*)d_in[11];
    const float* W_xo   = (const float*)d_in[12];
    const float* W_ho   = (const float*)d_in[13];
    const float* b_o    = (const float*)d_in[14];

    float* out_h = (float*)d_out;
    float* out_c = out_h + (size_t)Mdim * Hdim;

    __hip_bfloat16* Abf = (__hip_bfloat16*)d_ws;
    __hip_bfloat16* Bbf = Abf + (size_t)Mdim * Kdim;

    build_A<<<4096, 256, 0, stream>>>(x_t, h_prev, Abf);
    build_B<<<4096, 256, 0, stream>>>(W_xi, W_hi, W_xf, W_hf, W_xg, W_hg, W_xo, W_ho, Bbf);

    lstm_gemm<<<dim3((Mdim / BM) * (Ndim / BN)), 512, 0, stream>>>(
        Abf, Bbf, c_prev, b_i, b_f, b_g, b_o, out_h, out_c);
}